// Round 1
// baseline (382.497 us; speedup 1.0000x reference)
//
#include <hip/hip_runtime.h>

// Problem constants (from reference): NV=4096, NH=4096, N=8192, h=0, p=1.
// Inputs: mu (f32, N), var (f32, N*N). Output: muTE (f32, N) ++ M (f32, N*N).
//
// Output layout in float4 (16B) chunks, c = chunk index, floats [4c, 4c+4):
//   muTE          : chunks [0, 2048)         -- only chunk 0 nonzero: {hp,-hp,0,0}
//   M row 0 (M[0,:]) : chunks [2048, 4096)   -- j0 = (c-2048)*4
//   M row 1 (M[1,:]) : chunks [4096, 6144)   -- j0 = (c-4096)*4
//   M col 0/1 (M[j,0..1], j>=2) : c = 2048*(j+1), c >= 6144, (c & 2047)==0
//   everything else  : zero
//
// Single fused kernel: every chunk written exactly once (no ordering hazard),
// saving the second dispatch + zero_fill->fixup serialization of the previous
// two-kernel version. Store traffic = 268,468,224 B (the write roofline).
#define NN 8192L
#define N16 16779264L  // (NN + NN*NN) / 4 float4 chunks

__global__ __launch_bounds__(256) void fused_kernel(
    const float* __restrict__ mu,
    const float* __restrict__ var,
    float4* __restrict__ out)
{
    long i = (long)blockIdx.x * blockDim.x + threadIdx.x;
    const long stride = (long)gridDim.x * blockDim.x;  // 2,097,152 -> 8 iters

    for (long c = i; c < N16; c += stride) {
        float4 f = {0.f, 0.f, 0.f, 0.f};

        if (c < 6144) {
            if (c == 0) {
                // muTE[h] = hp, muTE[p] = -hp
                float hp = var[1];
                f.x = hp; f.y = -hp;
            } else if (c >= 2048) {
                // M row 0 or row 1 (coalesced: consecutive chunks ->
                // consecutive threads -> consecutive j0)
                bool row0 = c < 4096;
                long j0 = (c - (row0 ? 2048 : 4096)) * 4;

                float mu0   = mu[0];
                float mu1   = mu[1];
                float var01 = var[1];       // nvar[h,p] = hp
                float var10 = var[NN];      // nvar[p,h]
                float hp    = var01;

                float4 m4 = *reinterpret_cast<const float4*>(mu + j0);
                float mj[4] = {m4.x, m4.y, m4.z, m4.w};
                float vv[4];
                #pragma unroll
                for (int k = 0; k < 4; ++k) {
                    long j = j0 + k;
                    float vj0 = var[j * NN];        // nvar[j,h]
                    float vj1 = var[j * NN + 1];    // nvar[j,p]
                    float v = -2.0f * mj[k] * mu1 * mu0 + mj[k] * var10
                              + mu1 * vj0 + mu0 * vj1;
                    vv[k] = row0 ? v : -v;
                }
                if (j0 == 0) {
                    // 2x2 special block overwrites v[0], v[1] slots
                    float var00 = var[0];
                    float var11 = var[NN + 1];
                    float n3_hhp = -2.0f*mu0*mu0*mu1 + 2.0f*mu0*var01 + mu1*var00;
                    float n3_hpp = -2.0f*mu0*mu1*mu1 + mu0*var11 + 2.0f*mu1*var01;
                    float n3_pph = -2.0f*mu1*mu1*mu0 + 2.0f*mu1*var10 + mu0*var11;
                    float chp = -n3_hhp + n3_hpp - hp;
                    if (row0) { vv[0] = 2.0f*n3_hhp + hp; vv[1] = chp; }
                    else      { vv[0] = chp; vv[1] = -2.0f*n3_pph + hp; }
                }
                f.x = vv[0]; f.y = vv[1]; f.z = vv[2]; f.w = vv[3];
            }
            // chunks 1..2047 (rest of muTE): stay zero
        } else if ((c & 2047) == 0) {
            // First 16B of M row j (j >= 2): M[j,0] = v[j], M[j,1] = -v[j]
            long j = (c >> 11) - 1;
            float mu0   = mu[0];
            float mu1   = mu[1];
            float var10 = var[NN];
            float muj = mu[j];
            float vj0 = var[j * NN];
            float vj1 = var[j * NN + 1];
            float v = -2.0f * muj * mu1 * mu0 + muj * var10
                      + mu1 * vj0 + mu0 * vj1;
            f.x = v; f.y = -v;
        }

        out[c] = f;
    }
}

extern "C" void kernel_launch(void* const* d_in, const int* in_sizes, int n_in,
                              void* d_out, int out_size, void* d_ws, size_t ws_size,
                              hipStream_t stream) {
    const float* mu  = (const float*)d_in[0];
    const float* var = (const float*)d_in[1];
    fused_kernel<<<8192, 256, 0, stream>>>(mu, var, (float4*)d_out);
}